// Round 5
// baseline (9498.516 us; speedup 1.0000x reference)
//
#include <hip/hip_runtime.h>
#include <hip/hip_bf16.h>
#include <cstdint>

#define B_   4
#define P_   8
#define N_   10000
#define C_   64
#define H_   256
#define E_   160000
#define HOR_ 4
#define BN_  (B_ * N_)     // 40000
#define MPAD 40064         // 313 * 128

typedef __bf16 bf16;
typedef __attribute__((ext_vector_type(8))) __bf16 bf16x8;
typedef __attribute__((ext_vector_type(4))) float f32x4;

__device__ __forceinline__ void gl2lds16(const bf16* g, bf16* l) {
    __builtin_amdgcn_global_load_lds(
        (const __attribute__((address_space(1))) void*)g,
        (__attribute__((address_space(3))) void*)l, 16, 0, 0);
}

// ---------------------------------------------------------------- GEMM ----
// C[M,N] = A[M,K] @ Bt[N,K]^T. Used for conv (BIAS+RELU, bf16 out) and
// proj (PROJ scatter to d_out).
template <int BIAS, int RELU, int OUTBF, int PROJ>
__global__ __launch_bounds__(256) void gemm_k(
    const bf16* __restrict__ A, const bf16* __restrict__ Bt,
    void* __restrict__ Cp, const float* __restrict__ bias,
    int K, int Nn, int tstep)
{
    __shared__ __align__(16) bf16 As[128 * 32];
    __shared__ __align__(16) bf16 Bs[128 * 32];

    const int tid  = threadIdx.x;
    const int m0   = blockIdx.y * 128;
    const int n0   = blockIdx.x * 128;
    const int wave = tid >> 6;
    const int lane = tid & 63;
    const int wm   = (wave >> 1) << 6;
    const int wn   = (wave & 1) << 6;
    const int lr   = lane & 15;
    const int kg   = lane >> 4;

    f32x4 acc[4][4] = {};

    const int r0 = tid >> 2;
    const int k0 = (tid & 3) << 3;

    for (int kk = 0; kk < K; kk += 32) {
        const bf16* ga = A  + (size_t)(m0 + r0) * K + kk + k0;
        const bf16* gb = Bt + (size_t)(n0 + r0) * K + kk + k0;
        gl2lds16(ga,                  As + tid * 8);
        gl2lds16(ga + 64 * (size_t)K, As + 2048 + tid * 8);
        gl2lds16(gb,                  Bs + tid * 8);
        gl2lds16(gb + 64 * (size_t)K, Bs + 2048 + tid * 8);
        __syncthreads();

        bf16x8 af[4], bfv[4];
#pragma unroll
        for (int i = 0; i < 4; ++i)
            af[i] = *reinterpret_cast<const bf16x8*>(&As[(wm + i * 16 + lr) * 32 + kg * 8]);
#pragma unroll
        for (int j = 0; j < 4; ++j)
            bfv[j] = *reinterpret_cast<const bf16x8*>(&Bs[(wn + j * 16 + lr) * 32 + kg * 8]);
#pragma unroll
        for (int i = 0; i < 4; ++i)
#pragma unroll
            for (int j = 0; j < 4; ++j)
                acc[i][j] = __builtin_amdgcn_mfma_f32_16x16x32_bf16(af[i], bfv[j], acc[i][j], 0, 0, 0);
        __syncthreads();
    }

#pragma unroll
    for (int i = 0; i < 4; ++i) {
#pragma unroll
        for (int j = 0; j < 4; ++j) {
#pragma unroll
            for (int v = 0; v < 4; ++v) {
                int row = m0 + wm + i * 16 + kg * 4 + v;
                int col = n0 + wn + j * 16 + lr;
                float val = acc[i][j][v];
                if (BIAS) val += bias[col];
                if (RELU) val = fmaxf(val, 0.f);
                if (PROJ) {
                    if (col < C_ && row < BN_) {
                        int b = row / N_, n = row - b * N_;
                        reinterpret_cast<float*>(Cp)[(((size_t)b * HOR_ + tstep) * N_ + n) * C_ + col] = val;
                    }
                } else if (OUTBF) {
                    reinterpret_cast<bf16*>(Cp)[(size_t)row * Nn + col] = (bf16)val;
                } else {
                    reinterpret_cast<float*>(Cp)[(size_t)row * Nn + col] = val;
                }
            }
        }
    }
}

// -------------------------------------------------------- fused GRU v3 ----
// Block = 128-row strip, ALL 768 gate cols. X,Hc staged full-K in LDS once
// (XOR-swizzled, conflict-free). Weights PRE-PACKED in per-wave fragment
// order: flat [jj(16)][k(8)][gate(6)][(lr*4+kg)(64)][8 elems]. Each loadW
// is six dense 1KB wave-loads from L2; prefetch distance 2.
__global__ __launch_bounds__(256, 1) void gru3_k(
    const bf16* __restrict__ X, bf16* __restrict__ H,
    const bf16* __restrict__ Wpk,
    const float* __restrict__ bih, const float* __restrict__ bhh)
{
    __shared__ __align__(16) bf16 Xs[128 * 256];   // 64 KB
    __shared__ __align__(16) bf16 Hs[128 * 256];   // 64 KB

    const int tid  = threadIdx.x;
    const int m0   = blockIdx.x * 128;
    const int wave = tid >> 6;
    const int lane = tid & 63;
    const int wm   = (wave >> 1) << 6;   // 0 / 64
    const int colw = wave & 1;           // which 16-col half of the 32-col j tile
    const int wn   = colw << 4;          // 0 / 16
    const int lr   = lane & 15;
    const int kg   = lane >> 4;          // 0..3

    const int laneoff = lr * 32 + kg * 8;   // (lr*4+kg)*8 elements

    auto loadW = [&](int t, bf16x8* dst) {
        int jj = ((t >> 3) << 1) | colw;
        const bf16* base = Wpk + (size_t)((jj * 8 + (t & 7)) * 6) * 512 + laneoff;
#pragma unroll
        for (int g = 0; g < 6; ++g)
            dst[g] = *reinterpret_cast<const bf16x8*>(base + g * 512);
    };

    // ---- stage X, Hc full-K into LDS with xor swizzle (slot = ch ^ row%32)
    for (int r = 0; r < 16; ++r) {
        int pi  = r * 256 + tid;          // 0..4095 pieces of 16 B
        int row = pi >> 5, ch = pi & 31;
        int s   = ch ^ (row & 31);
        float4 vx = *reinterpret_cast<const float4*>(X + (size_t)(m0 + row) * 256 + ch * 8);
        float4 vh = *reinterpret_cast<const float4*>(H + (size_t)(m0 + row) * 256 + ch * 8);
        *reinterpret_cast<float4*>(&Xs[row * 256 + s * 8]) = vx;
        *reinterpret_cast<float4*>(&Hs[row * 256 + s * 8]) = vh;
    }

    bf16x8 bw[3][6];
    loadW(0, bw[0]);
    loadW(1, bw[1]);

    __syncthreads();

    f32x4 acc[6][4] = {};

    for (int t = 0; t < 64; ++t) {
        if (t < 62) loadW(t + 2, bw[(t + 2) % 3]);

        bf16x8 af[4], ah[4];
        const int ch = (t & 7) * 4 + kg;
#pragma unroll
        for (int i = 0; i < 4; ++i) {
            int row = wm + i * 16 + lr;
            int s   = ch ^ (row & 31);
            af[i] = *reinterpret_cast<const bf16x8*>(&Xs[row * 256 + s * 8]);
            ah[i] = *reinterpret_cast<const bf16x8*>(&Hs[row * 256 + s * 8]);
        }
        const bf16x8* w = bw[t % 3];
#pragma unroll
        for (int g = 0; g < 3; ++g)
#pragma unroll
            for (int i = 0; i < 4; ++i)
                acc[g][i] = __builtin_amdgcn_mfma_f32_16x16x32_bf16(af[i], w[g], acc[g][i], 0, 0, 0);
#pragma unroll
        for (int g = 3; g < 6; ++g)
#pragma unroll
            for (int i = 0; i < 4; ++i)
                acc[g][i] = __builtin_amdgcn_mfma_f32_16x16x32_bf16(ah[i], w[g], acc[g][i], 0, 0, 0);

        if ((t & 7) == 7) {
            const int j   = t >> 3;
            const int col = j * 32 + wn + lr;
            const float bi_r = bih[col], bi_z = bih[256 + col], bi_n = bih[512 + col];
            const float bh_r = bhh[col], bh_z = bhh[256 + col], bh_n = bhh[512 + col];
            const int hch = col >> 3, hel = col & 7;
#pragma unroll
            for (int i = 0; i < 4; ++i) {
#pragma unroll
                for (int v = 0; v < 4; ++v) {
                    int row = wm + i * 16 + kg * 4 + v;
                    float ir  = acc[0][i][v] + bi_r;
                    float iz  = acc[1][i][v] + bi_z;
                    float in_ = acc[2][i][v] + bi_n;
                    float hr  = acc[3][i][v] + bh_r;
                    float hz  = acc[4][i][v] + bh_z;
                    float hn  = acc[5][i][v] + bh_n;
                    float rr = __fdividef(1.f, 1.f + __expf(-(ir + hr)));
                    float zz = __fdividef(1.f, 1.f + __expf(-(iz + hz)));
                    float a  = in_ + rr * hn;
                    a = fminf(fmaxf(a, -15.f), 15.f);
                    float t2 = __expf(2.f * a);
                    float nn = __fdividef(t2 - 1.f, t2 + 1.f);
                    int hs = hch ^ (row & 31);
                    float hold = (float)Hs[row * 256 + hs * 8 + hel];
                    H[(size_t)(m0 + row) * 256 + col] = (bf16)((1.f - zz) * nn + zz * hold);
                }
            }
#pragma unroll
            for (int g = 0; g < 6; ++g)
#pragma unroll
                for (int i = 0; i < 4; ++i)
                    acc[g][i] = (f32x4){0.f, 0.f, 0.f, 0.f};
        }
    }
}

// ------------------------------------------------- weight pre-packing ----
// dst flat element = ((jj*8 + k)*6 + g)*512 + (lr*4 + kg)*8 + e
// src = (g<3 ? Wih : Whh)[(g%3)*256 + jj*16 + lr][k*32 + kg*8 + e]  (fp32)
__global__ void pack_w_k(const float* __restrict__ Wih, const float* __restrict__ Whh,
                         bf16* __restrict__ dst) {
    int idx = blockIdx.x * 256 + threadIdx.x;     // one thread = 8 elems
    if (idx >= 16 * 8 * 6 * 64) return;
    int lane = idx & 63;
    int r = idx >> 6;
    int g = r % 6; r /= 6;
    int k = r % 8; r /= 8;
    int jj = r;
    int lr = lane & 15, kg = lane >> 4;
    const float* src = (g < 3 ? Wih : Whh) + (size_t)((g % 3) * 256 + jj * 16 + lr) * 256 + k * 32 + kg * 8;
    bf16* d = dst + (size_t)((jj * 8 + k) * 6 + g) * 512 + (lr * 4 + kg) * 8;
#pragma unroll
    for (int e = 0; e < 8; ++e) d[e] = (bf16)src[e];
}

// ------------------------------------------------- conv A-matrix build ----
struct __attribute__((aligned(8))) bf4 { bf16 b[4]; };

__global__ __launch_bounds__(256) void gather_conv_k(
    const float* __restrict__ xbase, long long sB, long long sN,
    const int* __restrict__ rp0, const int* __restrict__ col0,
    const int* __restrict__ rp1, const int* __restrict__ col1,
    bf16* __restrict__ Aconv)
{
    int wid  = (blockIdx.x * 256 + threadIdx.x) >> 6;
    int lane = threadIdx.x & 63;
    if (wid >= BN_) return;
    int b = wid / N_;
    int n = wid - b * N_;
    int eg = lane >> 4;
    int cl = lane & 15;
    const float* xb = xbase + (size_t)b * sB;

    float4 xv = *reinterpret_cast<const float4*>(&xb[(size_t)n * sN + cl * 4]);

    float4 s0 = {0.f, 0.f, 0.f, 0.f};
    int st = rp0[n], en = rp0[n + 1];
    float d0 = fmaxf((float)(en - st), 1.f);
    for (int e = st + eg; e < en; e += 4) {
        const float4 v = *reinterpret_cast<const float4*>(&xb[(size_t)col0[e] * sN + cl * 4]);
        s0.x += v.x; s0.y += v.y; s0.z += v.z; s0.w += v.w;
    }

    float4 s1 = {0.f, 0.f, 0.f, 0.f};
    st = rp1[n]; en = rp1[n + 1];
    float d1 = fmaxf((float)(en - st), 1.f);
    for (int e = st + eg; e < en; e += 4) {
        const float4 v = *reinterpret_cast<const float4*>(&xb[(size_t)col1[e] * sN + cl * 4]);
        s1.x += v.x; s1.y += v.y; s1.z += v.z; s1.w += v.w;
    }

#pragma unroll
    for (int m = 16; m <= 32; m <<= 1) {
        s0.x += __shfl_xor(s0.x, m, 64); s0.y += __shfl_xor(s0.y, m, 64);
        s0.z += __shfl_xor(s0.z, m, 64); s0.w += __shfl_xor(s0.w, m, 64);
        s1.x += __shfl_xor(s1.x, m, 64); s1.y += __shfl_xor(s1.y, m, 64);
        s1.z += __shfl_xor(s1.z, m, 64); s1.w += __shfl_xor(s1.w, m, 64);
    }

    if (eg == 0) {
        float r0 = 1.f / d0, r1 = 1.f / d1;
        bf16* row = Aconv + (size_t)wid * 192;
        bf4 o;
        o.b[0] = (bf16)(s0.x * r0); o.b[1] = (bf16)(s0.y * r0);
        o.b[2] = (bf16)(s0.z * r0); o.b[3] = (bf16)(s0.w * r0);
        *reinterpret_cast<bf4*>(&row[cl * 4]) = o;
        o.b[0] = (bf16)xv.x; o.b[1] = (bf16)xv.y; o.b[2] = (bf16)xv.z; o.b[3] = (bf16)xv.w;
        *reinterpret_cast<bf4*>(&row[64 + cl * 4]) = o;
        o.b[0] = (bf16)(s1.x * r1); o.b[1] = (bf16)(s1.y * r1);
        o.b[2] = (bf16)(s1.z * r1); o.b[3] = (bf16)(s1.w * r1);
        *reinterpret_cast<bf4*>(&row[128 + cl * 4]) = o;
    }
}

// ------------------------------------------------------------ CSR build ----
__global__ void count_k(const int* __restrict__ ei, int* __restrict__ cnt) {
    int e = blockIdx.x * 256 + threadIdx.x;
    if (e < E_) atomicAdd(&cnt[ei[E_ + e]], 1);
}

__global__ __launch_bounds__(1024) void scan_k(
    const int* __restrict__ cnt, int* __restrict__ rp, int* __restrict__ fill)
{
    __shared__ int sums[1024];
    int t = threadIdx.x;
    const int chunk = 10;
    int lo = t * chunk;
    int hi = lo + chunk; if (hi > N_) hi = N_;
    int s = 0;
    for (int i = lo; i < hi; ++i) s += cnt[i];
    sums[t] = s;
    __syncthreads();
    for (int off = 1; off < 1024; off <<= 1) {
        int u = (t >= off) ? sums[t - off] : 0;
        __syncthreads();
        sums[t] += u;
        __syncthreads();
    }
    int base = (t == 0) ? 0 : sums[t - 1];
    for (int i = lo; i < hi; ++i) { rp[i] = base; fill[i] = base; base += cnt[i]; }
    if (t == 1023) rp[N_] = sums[1023];
}

__global__ void fill_k(const int* __restrict__ ei, int* __restrict__ fill,
                       int* __restrict__ colarr) {
    int e = blockIdx.x * 256 + threadIdx.x;
    if (e < E_) {
        int p = atomicAdd(&fill[ei[E_ + e]], 1);
        colarr[p] = ei[e];
    }
}

// --------------------------------------------------------- weight prep ----
__global__ void build_conv_bt_k(const float* __restrict__ Wl0, const float* __restrict__ Wr0,
                                const float* __restrict__ Wl1, const float* __restrict__ Wr1,
                                bf16* __restrict__ Bt) {
    int idx = blockIdx.x * 256 + threadIdx.x;
    if (idx >= 256 * 192) return;
    int n = idx / 192, k = idx - n * 192;
    float v;
    if (k < 64)       v = Wl0[k * 256 + n];
    else if (k < 128) v = Wr0[(k - 64) * 256 + n] + Wr1[(k - 64) * 256 + n];
    else              v = Wl1[(k - 128) * 256 + n];
    Bt[idx] = (bf16)v;
}

__global__ void build_conv_bias_k(const float* __restrict__ bl0, const float* __restrict__ bl1,
                                  float* __restrict__ bias) {
    int i = threadIdx.x;
    if (i < 256) bias[i] = bl0[i] + bl1[i];
}

__global__ void build_proj_k(const float* __restrict__ Wp, const float* __restrict__ bp,
                             bf16* __restrict__ Bt, float* __restrict__ bias) {
    int idx = blockIdx.x * 256 + threadIdx.x;
    if (idx < 128 * 256) {
        int n = idx >> 8, k = idx & 255;
        Bt[idx] = (bf16)(n < 64 ? Wp[n * 256 + k] : 0.f);
    }
    if (idx < 128) bias[idx] = (idx < 64) ? bp[idx] : 0.f;
}

// ---------------------------------------------------------------- host ----
extern "C" void kernel_launch(void* const* d_in, const int* in_sizes, int n_in,
                              void* d_out, int out_size, void* d_ws, size_t ws_size,
                              hipStream_t stream)
{
    const float* x_seq = (const float*)d_in[0];
    const int*   ei0   = (const int*)d_in[1];
    const int*   ei1   = (const int*)d_in[2];
    const float* Wl0   = (const float*)d_in[3];
    const float* bl0   = (const float*)d_in[4];
    const float* Wr0   = (const float*)d_in[5];
    const float* Wl1   = (const float*)d_in[6];
    const float* bl1   = (const float*)d_in[7];
    const float* Wr1   = (const float*)d_in[8];
    const float* Wp    = (const float*)d_in[9];
    const float* bp    = (const float*)d_in[10];
    const float* gWih[3], *gWhh[3], *gbih[3], *gbhh[3];
    for (int g = 0; g < 3; ++g) {
        gWih[g] = (const float*)d_in[11 + 4 * g];
        gWhh[g] = (const float*)d_in[12 + 4 * g];
        gbih[g] = (const float*)d_in[13 + 4 * g];
        gbhh[g] = (const float*)d_in[14 + 4 * g];
    }

    char* p = (char*)d_ws;
    auto alloc = [&](size_t bytes) -> char* {
        char* r = p; p += (bytes + 255) & ~(size_t)255; return r;
    };
    bf16*  Aconv  = (bf16*)alloc((size_t)MPAD * 192 * 2);
    bf16*  cbuf   = (bf16*)alloc((size_t)MPAD * 256 * 2);
    bf16*  h[3];
    for (int g = 0; g < 3; ++g) h[g] = (bf16*)alloc((size_t)MPAD * 256 * 2);
    bf16*  wpk[3];
    for (int g = 0; g < 3; ++g) wpk[g] = (bf16*)alloc((size_t)16 * 8 * 6 * 512 * 2);
    bf16*  btconv = (bf16*)alloc((size_t)256 * 192 * 2);
    float* bconv  = (float*)alloc(256 * 4);
    bf16*  btproj = (bf16*)alloc((size_t)128 * 256 * 2);
    float* bproj  = (float*)alloc(128 * 4);
    int* cnt0  = (int*)alloc(N_ * 4);
    int* cnt1  = (int*)alloc(N_ * 4);
    int* rp0   = (int*)alloc((N_ + 1) * 4);
    int* rp1   = (int*)alloc((N_ + 1) * 4);
    int* fill0 = (int*)alloc((N_ + 1) * 4);
    int* fill1 = (int*)alloc((N_ + 1) * 4);
    int* col0  = (int*)alloc(E_ * 4);
    int* col1  = (int*)alloc(E_ * 4);

    hipMemsetAsync(Aconv, 0, (size_t)MPAD * 192 * 2, stream);
    for (int g = 0; g < 3; ++g)
        hipMemsetAsync(h[g], 0, (size_t)MPAD * 256 * 2, stream);
    hipMemsetAsync(cnt0, 0, N_ * 4, stream);
    hipMemsetAsync(cnt1, 0, N_ * 4, stream);

    for (int g = 0; g < 3; ++g)
        pack_w_k<<<192, 256, 0, stream>>>(gWih[g], gWhh[g], wpk[g]);
    build_conv_bt_k<<<192, 256, 0, stream>>>(Wl0, Wr0, Wl1, Wr1, btconv);
    build_conv_bias_k<<<1, 256, 0, stream>>>(bl0, bl1, bconv);
    build_proj_k<<<128, 256, 0, stream>>>(Wp, bp, btproj, bproj);

    count_k<<<(E_ + 255) / 256, 256, 0, stream>>>(ei0, cnt0);
    count_k<<<(E_ + 255) / 256, 256, 0, stream>>>(ei1, cnt1);
    scan_k<<<1, 1024, 0, stream>>>(cnt0, rp0, fill0);
    scan_k<<<1, 1024, 0, stream>>>(cnt1, rp1, fill1);
    fill_k<<<(E_ + 255) / 256, 256, 0, stream>>>(ei0, fill0, col0);
    fill_k<<<(E_ + 255) / 256, 256, 0, stream>>>(ei1, fill1, col1);

    auto do_conv = [&](const float* xb, long long sB, long long sN) {
        gather_conv_k<<<10000, 256, 0, stream>>>(xb, sB, sN, rp0, col0, rp1, col1, Aconv);
        gemm_k<1, 1, 1, 0><<<dim3(2, 313, 1), 256, 0, stream>>>(
            Aconv, btconv, cbuf, bconv, 192, 256, 0);
    };
    auto do_grus = [&]() {
        gru3_k<<<313, 256, 0, stream>>>(cbuf, h[0], wpk[0], gbih[0], gbhh[0]);
        gru3_k<<<313, 256, 0, stream>>>(h[0], h[1], wpk[1], gbih[1], gbhh[1]);
        gru3_k<<<313, 256, 0, stream>>>(h[1], h[2], wpk[2], gbih[2], gbhh[2]);
    };

    // encoder
    for (int ps = 0; ps < P_; ++ps) {
        do_conv(x_seq + (size_t)ps * N_ * C_, (long long)P_ * N_ * C_, C_);
        do_grus();
    }

    // decoder: t=0 reuses encoder step-7 conv output (same x input)
    float* out = (float*)d_out;
    for (int t = 0; t < HOR_; ++t) {
        if (t > 0)
            do_conv(out + (size_t)(t - 1) * N_ * C_, (long long)HOR_ * N_ * C_, C_);
        do_grus();
        gemm_k<1, 0, 0, 1><<<dim3(1, 313, 1), 256, 0, stream>>>(
            h[2], btproj, out, bproj, 256, 128, t);
    }
}

// Round 6
// 5343.009 us; speedup vs baseline: 1.7777x; 1.7777x over previous
//
#include <hip/hip_runtime.h>
#include <hip/hip_bf16.h>
#include <cstdint>

#define B_   4
#define P_   8
#define N_   10000
#define C_   64
#define H_   256
#define E_   160000
#define HOR_ 4
#define BN_  (B_ * N_)     // 40000
#define MPAD 40064         // 313 * 128

typedef __bf16 bf16;
typedef __attribute__((ext_vector_type(8))) __bf16 bf16x8;
typedef __attribute__((ext_vector_type(4))) float f32x4;

__device__ __forceinline__ void gl2lds16(const bf16* g, bf16* l) {
    __builtin_amdgcn_global_load_lds(
        (const __attribute__((address_space(1))) void*)g,
        (__attribute__((address_space(3))) void*)l, 16, 0, 0);
}

// ---------------------------------------------------------------- GEMM ----
// C[M,N] = A[M,K] @ Bt[N,K]^T. Used for conv (BIAS+RELU, bf16 out) and
// proj (PROJ scatter to d_out).
template <int BIAS, int RELU, int OUTBF, int PROJ>
__global__ __launch_bounds__(256) void gemm_k(
    const bf16* __restrict__ A, const bf16* __restrict__ Bt,
    void* __restrict__ Cp, const float* __restrict__ bias,
    int K, int Nn, int tstep)
{
    __shared__ __align__(16) bf16 As[128 * 32];
    __shared__ __align__(16) bf16 Bs[128 * 32];

    const int tid  = threadIdx.x;
    const int m0   = blockIdx.y * 128;
    const int n0   = blockIdx.x * 128;
    const int wave = tid >> 6;
    const int lane = tid & 63;
    const int wm   = (wave >> 1) << 6;
    const int wn   = (wave & 1) << 6;
    const int lr   = lane & 15;
    const int kg   = lane >> 4;

    f32x4 acc[4][4] = {};

    const int r0 = tid >> 2;
    const int k0 = (tid & 3) << 3;

    for (int kk = 0; kk < K; kk += 32) {
        const bf16* ga = A  + (size_t)(m0 + r0) * K + kk + k0;
        const bf16* gb = Bt + (size_t)(n0 + r0) * K + kk + k0;
        gl2lds16(ga,                  As + tid * 8);
        gl2lds16(ga + 64 * (size_t)K, As + 2048 + tid * 8);
        gl2lds16(gb,                  Bs + tid * 8);
        gl2lds16(gb + 64 * (size_t)K, Bs + 2048 + tid * 8);
        __syncthreads();

        bf16x8 af[4], bfv[4];
#pragma unroll
        for (int i = 0; i < 4; ++i)
            af[i] = *reinterpret_cast<const bf16x8*>(&As[(wm + i * 16 + lr) * 32 + kg * 8]);
#pragma unroll
        for (int j = 0; j < 4; ++j)
            bfv[j] = *reinterpret_cast<const bf16x8*>(&Bs[(wn + j * 16 + lr) * 32 + kg * 8]);
#pragma unroll
        for (int i = 0; i < 4; ++i)
#pragma unroll
            for (int j = 0; j < 4; ++j)
                acc[i][j] = __builtin_amdgcn_mfma_f32_16x16x32_bf16(af[i], bfv[j], acc[i][j], 0, 0, 0);
        __syncthreads();
    }

#pragma unroll
    for (int i = 0; i < 4; ++i) {
#pragma unroll
        for (int j = 0; j < 4; ++j) {
#pragma unroll
            for (int v = 0; v < 4; ++v) {
                int row = m0 + wm + i * 16 + kg * 4 + v;
                int col = n0 + wn + j * 16 + lr;
                float val = acc[i][j][v];
                if (BIAS) val += bias[col];
                if (RELU) val = fmaxf(val, 0.f);
                if (PROJ) {
                    if (col < C_ && row < BN_) {
                        int b = row / N_, n = row - b * N_;
                        reinterpret_cast<float*>(Cp)[(((size_t)b * HOR_ + tstep) * N_ + n) * C_ + col] = val;
                    }
                } else if (OUTBF) {
                    reinterpret_cast<bf16*>(Cp)[(size_t)row * Nn + col] = (bf16)val;
                } else {
                    reinterpret_cast<float*>(Cp)[(size_t)row * Nn + col] = val;
                }
            }
        }
    }
}

// -------------------------------------------------------- fused GRU v4 ----
// Block = 128-row strip, ALL 768 gate cols. X,Hc staged full-K in LDS once
// (XOR-swizzled, conflict-free). Weights PRE-PACKED in per-wave fragment
// order: flat [jj(16)][k(8)][gate(6)][(lr*4+kg)(64)][8 elems]; dense 1KB
// wave-loads from L2. Prefetch distance 2 with a 4-slot rotation whose
// indices are ALL compile-time (outer tb += 4, inner u unrolled) — v3's
// `% 3` dynamic indexing spilled the buffer to scratch (WRITE_SIZE 342MB).
__global__ __launch_bounds__(256, 1) void gru4_k(
    const bf16* __restrict__ X, bf16* __restrict__ H,
    const bf16* __restrict__ Wpk,
    const float* __restrict__ bih, const float* __restrict__ bhh)
{
    __shared__ __align__(16) bf16 Xs[128 * 256];   // 64 KB
    __shared__ __align__(16) bf16 Hs[128 * 256];   // 64 KB

    const int tid  = threadIdx.x;
    const int m0   = blockIdx.x * 128;
    const int wave = tid >> 6;
    const int lane = tid & 63;
    const int wm   = (wave >> 1) << 6;   // 0 / 64
    const int colw = wave & 1;           // which 16-col half of the 32-col j tile
    const int wn   = colw << 4;          // 0 / 16
    const int lr   = lane & 15;
    const int kg   = lane >> 4;          // 0..3

    const int laneoff = lr * 32 + kg * 8;   // (lr*4+kg)*8 elements

    auto loadW = [&](int t, bf16x8* dst) {
        int jj = ((t >> 3) << 1) | colw;
        const bf16* base = Wpk + (size_t)((jj * 8 + (t & 7)) * 6) * 512 + laneoff;
#pragma unroll
        for (int g = 0; g < 6; ++g)
            dst[g] = *reinterpret_cast<const bf16x8*>(base + g * 512);
    };

    // ---- stage X, Hc full-K into LDS with xor swizzle (slot = ch ^ row%32)
    for (int r = 0; r < 16; ++r) {
        int pi  = r * 256 + tid;          // 0..4095 pieces of 16 B
        int row = pi >> 5, ch = pi & 31;
        int s   = ch ^ (row & 31);
        float4 vx = *reinterpret_cast<const float4*>(X + (size_t)(m0 + row) * 256 + ch * 8);
        float4 vh = *reinterpret_cast<const float4*>(H + (size_t)(m0 + row) * 256 + ch * 8);
        *reinterpret_cast<float4*>(&Xs[row * 256 + s * 8]) = vx;
        *reinterpret_cast<float4*>(&Hs[row * 256 + s * 8]) = vh;
    }

    bf16x8 bw[4][6];
    loadW(0, bw[0]);
    loadW(1, bw[1]);

    __syncthreads();

    f32x4 acc[6][4] = {};

    for (int tb = 0; tb < 64; tb += 4) {
#pragma unroll
        for (int u = 0; u < 4; ++u) {
            const int t = tb + u;                         // t & 3 == u
            if (t + 2 < 64) loadW(t + 2, bw[(u + 2) & 3]); // slot index compile-time

            bf16x8 af[4], ah[4];
            const int ch = (t & 7) * 4 + kg;
#pragma unroll
            for (int i = 0; i < 4; ++i) {
                int row = wm + i * 16 + lr;
                int s   = ch ^ (row & 31);
                af[i] = *reinterpret_cast<const bf16x8*>(&Xs[row * 256 + s * 8]);
                ah[i] = *reinterpret_cast<const bf16x8*>(&Hs[row * 256 + s * 8]);
            }
            const bf16x8* w = bw[u];
#pragma unroll
            for (int g = 0; g < 3; ++g)
#pragma unroll
                for (int i = 0; i < 4; ++i)
                    acc[g][i] = __builtin_amdgcn_mfma_f32_16x16x32_bf16(af[i], w[g], acc[g][i], 0, 0, 0);
#pragma unroll
            for (int g = 3; g < 6; ++g)
#pragma unroll
                for (int i = 0; i < 4; ++i)
                    acc[g][i] = __builtin_amdgcn_mfma_f32_16x16x32_bf16(ah[i], w[g], acc[g][i], 0, 0, 0);

            if ((t & 7) == 7) {
                const int j   = t >> 3;
                const int col = j * 32 + wn + lr;
                const float bi_r = bih[col], bi_z = bih[256 + col], bi_n = bih[512 + col];
                const float bh_r = bhh[col], bh_z = bhh[256 + col], bh_n = bhh[512 + col];
                const int hch = col >> 3, hel = col & 7;
#pragma unroll
                for (int i = 0; i < 4; ++i) {
#pragma unroll
                    for (int v = 0; v < 4; ++v) {
                        int row = wm + i * 16 + kg * 4 + v;
                        float ir  = acc[0][i][v] + bi_r;
                        float iz  = acc[1][i][v] + bi_z;
                        float in_ = acc[2][i][v] + bi_n;
                        float hr  = acc[3][i][v] + bh_r;
                        float hz  = acc[4][i][v] + bh_z;
                        float hn  = acc[5][i][v] + bh_n;
                        float rr = __fdividef(1.f, 1.f + __expf(-(ir + hr)));
                        float zz = __fdividef(1.f, 1.f + __expf(-(iz + hz)));
                        float a  = in_ + rr * hn;
                        a = fminf(fmaxf(a, -15.f), 15.f);
                        float t2 = __expf(2.f * a);
                        float nn = __fdividef(t2 - 1.f, t2 + 1.f);
                        int hs = hch ^ (row & 31);
                        float hold = (float)Hs[row * 256 + hs * 8 + hel];
                        H[(size_t)(m0 + row) * 256 + col] = (bf16)((1.f - zz) * nn + zz * hold);
                    }
                }
#pragma unroll
                for (int g = 0; g < 6; ++g)
#pragma unroll
                    for (int i = 0; i < 4; ++i)
                        acc[g][i] = (f32x4){0.f, 0.f, 0.f, 0.f};
            }
        }
    }
}

// ------------------------------------------------- weight pre-packing ----
// dst flat element = ((jj*8 + k)*6 + g)*512 + (lr*4 + kg)*8 + e
// src = (g<3 ? Wih : Whh)[(g%3)*256 + jj*16 + lr][k*32 + kg*8 + e]  (fp32)
__global__ void pack_w_k(const float* __restrict__ Wih, const float* __restrict__ Whh,
                         bf16* __restrict__ dst) {
    int idx = blockIdx.x * 256 + threadIdx.x;     // one thread = 8 elems
    if (idx >= 16 * 8 * 6 * 64) return;
    int lane = idx & 63;
    int r = idx >> 6;
    int g = r % 6; r /= 6;
    int k = r % 8; r /= 8;
    int jj = r;
    int lr = lane & 15, kg = lane >> 4;
    const float* src = (g < 3 ? Wih : Whh) + (size_t)((g % 3) * 256 + jj * 16 + lr) * 256 + k * 32 + kg * 8;
    bf16* d = dst + (size_t)((jj * 8 + k) * 6 + g) * 512 + (lr * 4 + kg) * 8;
#pragma unroll
    for (int e = 0; e < 8; ++e) d[e] = (bf16)src[e];
}

// ------------------------------------------------- conv A-matrix build ----
struct __attribute__((aligned(8))) bf4 { bf16 b[4]; };

__global__ __launch_bounds__(256) void gather_conv_k(
    const float* __restrict__ xbase, long long sB, long long sN,
    const int* __restrict__ rp0, const int* __restrict__ col0,
    const int* __restrict__ rp1, const int* __restrict__ col1,
    bf16* __restrict__ Aconv)
{
    int wid  = (blockIdx.x * 256 + threadIdx.x) >> 6;
    int lane = threadIdx.x & 63;
    if (wid >= BN_) return;
    int b = wid / N_;
    int n = wid - b * N_;
    int eg = lane >> 4;
    int cl = lane & 15;
    const float* xb = xbase + (size_t)b * sB;

    float4 xv = *reinterpret_cast<const float4*>(&xb[(size_t)n * sN + cl * 4]);

    float4 s0 = {0.f, 0.f, 0.f, 0.f};
    int st = rp0[n], en = rp0[n + 1];
    float d0 = fmaxf((float)(en - st), 1.f);
    for (int e = st + eg; e < en; e += 4) {
        const float4 v = *reinterpret_cast<const float4*>(&xb[(size_t)col0[e] * sN + cl * 4]);
        s0.x += v.x; s0.y += v.y; s0.z += v.z; s0.w += v.w;
    }

    float4 s1 = {0.f, 0.f, 0.f, 0.f};
    st = rp1[n]; en = rp1[n + 1];
    float d1 = fmaxf((float)(en - st), 1.f);
    for (int e = st + eg; e < en; e += 4) {
        const float4 v = *reinterpret_cast<const float4*>(&xb[(size_t)col1[e] * sN + cl * 4]);
        s1.x += v.x; s1.y += v.y; s1.z += v.z; s1.w += v.w;
    }

#pragma unroll
    for (int m = 16; m <= 32; m <<= 1) {
        s0.x += __shfl_xor(s0.x, m, 64); s0.y += __shfl_xor(s0.y, m, 64);
        s0.z += __shfl_xor(s0.z, m, 64); s0.w += __shfl_xor(s0.w, m, 64);
        s1.x += __shfl_xor(s1.x, m, 64); s1.y += __shfl_xor(s1.y, m, 64);
        s1.z += __shfl_xor(s1.z, m, 64); s1.w += __shfl_xor(s1.w, m, 64);
    }

    if (eg == 0) {
        float r0 = 1.f / d0, r1 = 1.f / d1;
        bf16* row = Aconv + (size_t)wid * 192;
        bf4 o;
        o.b[0] = (bf16)(s0.x * r0); o.b[1] = (bf16)(s0.y * r0);
        o.b[2] = (bf16)(s0.z * r0); o.b[3] = (bf16)(s0.w * r0);
        *reinterpret_cast<bf4*>(&row[cl * 4]) = o;
        o.b[0] = (bf16)xv.x; o.b[1] = (bf16)xv.y; o.b[2] = (bf16)xv.z; o.b[3] = (bf16)xv.w;
        *reinterpret_cast<bf4*>(&row[64 + cl * 4]) = o;
        o.b[0] = (bf16)(s1.x * r1); o.b[1] = (bf16)(s1.y * r1);
        o.b[2] = (bf16)(s1.z * r1); o.b[3] = (bf16)(s1.w * r1);
        *reinterpret_cast<bf4*>(&row[128 + cl * 4]) = o;
    }
}

// ------------------------------------------------------------ CSR build ----
__global__ void count_k(const int* __restrict__ ei, int* __restrict__ cnt) {
    int e = blockIdx.x * 256 + threadIdx.x;
    if (e < E_) atomicAdd(&cnt[ei[E_ + e]], 1);
}

__global__ __launch_bounds__(1024) void scan_k(
    const int* __restrict__ cnt, int* __restrict__ rp, int* __restrict__ fill)
{
    __shared__ int sums[1024];
    int t = threadIdx.x;
    const int chunk = 10;
    int lo = t * chunk;
    int hi = lo + chunk; if (hi > N_) hi = N_;
    int s = 0;
    for (int i = lo; i < hi; ++i) s += cnt[i];
    sums[t] = s;
    __syncthreads();
    for (int off = 1; off < 1024; off <<= 1) {
        int u = (t >= off) ? sums[t - off] : 0;
        __syncthreads();
        sums[t] += u;
        __syncthreads();
    }
    int base = (t == 0) ? 0 : sums[t - 1];
    for (int i = lo; i < hi; ++i) { rp[i] = base; fill[i] = base; base += cnt[i]; }
    if (t == 1023) rp[N_] = sums[1023];
}

__global__ void fill_k(const int* __restrict__ ei, int* __restrict__ fill,
                       int* __restrict__ colarr) {
    int e = blockIdx.x * 256 + threadIdx.x;
    if (e < E_) {
        int p = atomicAdd(&fill[ei[E_ + e]], 1);
        colarr[p] = ei[e];
    }
}

// --------------------------------------------------------- weight prep ----
__global__ void build_conv_bt_k(const float* __restrict__ Wl0, const float* __restrict__ Wr0,
                                const float* __restrict__ Wl1, const float* __restrict__ Wr1,
                                bf16* __restrict__ Bt) {
    int idx = blockIdx.x * 256 + threadIdx.x;
    if (idx >= 256 * 192) return;
    int n = idx / 192, k = idx - n * 192;
    float v;
    if (k < 64)       v = Wl0[k * 256 + n];
    else if (k < 128) v = Wr0[(k - 64) * 256 + n] + Wr1[(k - 64) * 256 + n];
    else              v = Wl1[(k - 128) * 256 + n];
    Bt[idx] = (bf16)v;
}

__global__ void build_conv_bias_k(const float* __restrict__ bl0, const float* __restrict__ bl1,
                                  float* __restrict__ bias) {
    int i = threadIdx.x;
    if (i < 256) bias[i] = bl0[i] + bl1[i];
}

__global__ void build_proj_k(const float* __restrict__ Wp, const float* __restrict__ bp,
                             bf16* __restrict__ Bt, float* __restrict__ bias) {
    int idx = blockIdx.x * 256 + threadIdx.x;
    if (idx < 128 * 256) {
        int n = idx >> 8, k = idx & 255;
        Bt[idx] = (bf16)(n < 64 ? Wp[n * 256 + k] : 0.f);
    }
    if (idx < 128) bias[idx] = (idx < 64) ? bp[idx] : 0.f;
}

// ---------------------------------------------------------------- host ----
extern "C" void kernel_launch(void* const* d_in, const int* in_sizes, int n_in,
                              void* d_out, int out_size, void* d_ws, size_t ws_size,
                              hipStream_t stream)
{
    const float* x_seq = (const float*)d_in[0];
    const int*   ei0   = (const int*)d_in[1];
    const int*   ei1   = (const int*)d_in[2];
    const float* Wl0   = (const float*)d_in[3];
    const float* bl0   = (const float*)d_in[4];
    const float* Wr0   = (const float*)d_in[5];
    const float* Wl1   = (const float*)d_in[6];
    const float* bl1   = (const float*)d_in[7];
    const float* Wr1   = (const float*)d_in[8];
    const float* Wp    = (const float*)d_in[9];
    const float* bp    = (const float*)d_in[10];
    const float* gWih[3], *gWhh[3], *gbih[3], *gbhh[3];
    for (int g = 0; g < 3; ++g) {
        gWih[g] = (const float*)d_in[11 + 4 * g];
        gWhh[g] = (const float*)d_in[12 + 4 * g];
        gbih[g] = (const float*)d_in[13 + 4 * g];
        gbhh[g] = (const float*)d_in[14 + 4 * g];
    }

    char* p = (char*)d_ws;
    auto alloc = [&](size_t bytes) -> char* {
        char* r = p; p += (bytes + 255) & ~(size_t)255; return r;
    };
    bf16*  Aconv  = (bf16*)alloc((size_t)MPAD * 192 * 2);
    bf16*  cbuf   = (bf16*)alloc((size_t)MPAD * 256 * 2);
    bf16*  h[3];
    for (int g = 0; g < 3; ++g) h[g] = (bf16*)alloc((size_t)MPAD * 256 * 2);
    bf16*  wpk[3];
    for (int g = 0; g < 3; ++g) wpk[g] = (bf16*)alloc((size_t)16 * 8 * 6 * 512 * 2);
    bf16*  btconv = (bf16*)alloc((size_t)256 * 192 * 2);
    float* bconv  = (float*)alloc(256 * 4);
    bf16*  btproj = (bf16*)alloc((size_t)128 * 256 * 2);
    float* bproj  = (float*)alloc(128 * 4);
    int* cnt0  = (int*)alloc(N_ * 4);
    int* cnt1  = (int*)alloc(N_ * 4);
    int* rp0   = (int*)alloc((N_ + 1) * 4);
    int* rp1   = (int*)alloc((N_ + 1) * 4);
    int* fill0 = (int*)alloc((N_ + 1) * 4);
    int* fill1 = (int*)alloc((N_ + 1) * 4);
    int* col0  = (int*)alloc(E_ * 4);
    int* col1  = (int*)alloc(E_ * 4);

    hipMemsetAsync(Aconv, 0, (size_t)MPAD * 192 * 2, stream);
    for (int g = 0; g < 3; ++g)
        hipMemsetAsync(h[g], 0, (size_t)MPAD * 256 * 2, stream);
    hipMemsetAsync(cnt0, 0, N_ * 4, stream);
    hipMemsetAsync(cnt1, 0, N_ * 4, stream);

    for (int g = 0; g < 3; ++g)
        pack_w_k<<<192, 256, 0, stream>>>(gWih[g], gWhh[g], wpk[g]);
    build_conv_bt_k<<<192, 256, 0, stream>>>(Wl0, Wr0, Wl1, Wr1, btconv);
    build_conv_bias_k<<<1, 256, 0, stream>>>(bl0, bl1, bconv);
    build_proj_k<<<128, 256, 0, stream>>>(Wp, bp, btproj, bproj);

    count_k<<<(E_ + 255) / 256, 256, 0, stream>>>(ei0, cnt0);
    count_k<<<(E_ + 255) / 256, 256, 0, stream>>>(ei1, cnt1);
    scan_k<<<1, 1024, 0, stream>>>(cnt0, rp0, fill0);
    scan_k<<<1, 1024, 0, stream>>>(cnt1, rp1, fill1);
    fill_k<<<(E_ + 255) / 256, 256, 0, stream>>>(ei0, fill0, col0);
    fill_k<<<(E_ + 255) / 256, 256, 0, stream>>>(ei1, fill1, col1);

    auto do_conv = [&](const float* xb, long long sB, long long sN) {
        gather_conv_k<<<10000, 256, 0, stream>>>(xb, sB, sN, rp0, col0, rp1, col1, Aconv);
        gemm_k<1, 1, 1, 0><<<dim3(2, 313, 1), 256, 0, stream>>>(
            Aconv, btconv, cbuf, bconv, 192, 256, 0);
    };
    auto do_grus = [&]() {
        gru4_k<<<313, 256, 0, stream>>>(cbuf, h[0], wpk[0], gbih[0], gbhh[0]);
        gru4_k<<<313, 256, 0, stream>>>(h[0], h[1], wpk[1], gbih[1], gbhh[1]);
        gru4_k<<<313, 256, 0, stream>>>(h[1], h[2], wpk[2], gbih[2], gbhh[2]);
    };

    // encoder
    for (int ps = 0; ps < P_; ++ps) {
        do_conv(x_seq + (size_t)ps * N_ * C_, (long long)P_ * N_ * C_, C_);
        do_grus();
    }

    // decoder: t=0 reuses encoder step-7 conv output (same x input)
    float* out = (float*)d_out;
    for (int t = 0; t < HOR_; ++t) {
        if (t > 0)
            do_conv(out + (size_t)(t - 1) * N_ * C_, (long long)HOR_ * N_ * C_, C_);
        do_grus();
        gemm_k<1, 0, 0, 1><<<dim3(1, 313, 1), 256, 0, stream>>>(
            h[2], btproj, out, bproj, 256, 128, t);
    }
}

// Round 7
// 2803.153 us; speedup vs baseline: 3.3885x; 1.9061x over previous
//
#include <hip/hip_runtime.h>
#include <hip/hip_bf16.h>
#include <cstdint>

#define B_   4
#define P_   8
#define N_   10000
#define C_   64
#define H_   256
#define E_   160000
#define HOR_ 4
#define BN_  (B_ * N_)     // 40000
#define MPAD 40064         // 313 * 128

typedef __bf16 bf16;
typedef __attribute__((ext_vector_type(8))) __bf16 bf16x8;
typedef __attribute__((ext_vector_type(4))) float f32x4;

__device__ __forceinline__ void gl2lds16(const bf16* g, bf16* l) {
    __builtin_amdgcn_global_load_lds(
        (const __attribute__((address_space(1))) void*)g,
        (__attribute__((address_space(3))) void*)l, 16, 0, 0);
}

// ---------------------------------------------------------------- GEMM ----
// C[M,N] = A[M,K] @ Bt[N,K]^T. Used for conv (BIAS+RELU, bf16 out) and
// proj (PROJ scatter to d_out).
template <int BIAS, int RELU, int OUTBF, int PROJ>
__global__ __launch_bounds__(256) void gemm_k(
    const bf16* __restrict__ A, const bf16* __restrict__ Bt,
    void* __restrict__ Cp, const float* __restrict__ bias,
    int K, int Nn, int tstep)
{
    __shared__ __align__(16) bf16 As[128 * 32];
    __shared__ __align__(16) bf16 Bs[128 * 32];

    const int tid  = threadIdx.x;
    const int m0   = blockIdx.y * 128;
    const int n0   = blockIdx.x * 128;
    const int wave = tid >> 6;
    const int lane = tid & 63;
    const int wm   = (wave >> 1) << 6;
    const int wn   = (wave & 1) << 6;
    const int lr   = lane & 15;
    const int kg   = lane >> 4;

    f32x4 acc[4][4] = {};

    const int r0 = tid >> 2;
    const int k0 = (tid & 3) << 3;

    for (int kk = 0; kk < K; kk += 32) {
        const bf16* ga = A  + (size_t)(m0 + r0) * K + kk + k0;
        const bf16* gb = Bt + (size_t)(n0 + r0) * K + kk + k0;
        gl2lds16(ga,                  As + tid * 8);
        gl2lds16(ga + 64 * (size_t)K, As + 2048 + tid * 8);
        gl2lds16(gb,                  Bs + tid * 8);
        gl2lds16(gb + 64 * (size_t)K, Bs + 2048 + tid * 8);
        __syncthreads();

        bf16x8 af[4], bfv[4];
#pragma unroll
        for (int i = 0; i < 4; ++i)
            af[i] = *reinterpret_cast<const bf16x8*>(&As[(wm + i * 16 + lr) * 32 + kg * 8]);
#pragma unroll
        for (int j = 0; j < 4; ++j)
            bfv[j] = *reinterpret_cast<const bf16x8*>(&Bs[(wn + j * 16 + lr) * 32 + kg * 8]);
#pragma unroll
        for (int i = 0; i < 4; ++i)
#pragma unroll
            for (int j = 0; j < 4; ++j)
                acc[i][j] = __builtin_amdgcn_mfma_f32_16x16x32_bf16(af[i], bfv[j], acc[i][j], 0, 0, 0);
        __syncthreads();
    }

#pragma unroll
    for (int i = 0; i < 4; ++i) {
#pragma unroll
        for (int j = 0; j < 4; ++j) {
#pragma unroll
            for (int v = 0; v < 4; ++v) {
                int row = m0 + wm + i * 16 + kg * 4 + v;
                int col = n0 + wn + j * 16 + lr;
                float val = acc[i][j][v];
                if (BIAS) val += bias[col];
                if (RELU) val = fmaxf(val, 0.f);
                if (PROJ) {
                    if (col < C_ && row < BN_) {
                        int b = row / N_, n = row - b * N_;
                        reinterpret_cast<float*>(Cp)[(((size_t)b * HOR_ + tstep) * N_ + n) * C_ + col] = val;
                    }
                } else if (OUTBF) {
                    reinterpret_cast<bf16*>(Cp)[(size_t)row * Nn + col] = (bf16)val;
                } else {
                    reinterpret_cast<float*>(Cp)[(size_t)row * Nn + col] = val;
                }
            }
        }
    }
}

// ----------------------------------------------------------- fused GRU ----
// Round-3 structure (128 rows x 32 gate-cols per block, 28 KB LDS, ~6
// waves/CU) + XCD-aware swizzle: linear id = 64*sblk + 8*jblk + (strip&7)
// so the 8 j-blocks sharing a row strip have id == strip (mod 8) -> same
// XCD -> X/H strip and the 786 KB weight set stay L2-resident per XCD.
__global__ __launch_bounds__(256, 2) void gru_fused_k(
    const bf16* __restrict__ X, const bf16* __restrict__ Hc,
    bf16* __restrict__ Hn,
    const bf16* __restrict__ Wih, const bf16* __restrict__ Whh,
    const float* __restrict__ bih, const float* __restrict__ bhh)
{
    const int id    = blockIdx.x;
    const int sblk  = id >> 6;
    const int jblk  = (id >> 3) & 7;
    const int slow  = id & 7;
    const int strip = (sblk << 3) | slow;
    if (strip >= 313) return;

    __shared__ __align__(16) bf16 Xs[128 * 32];
    __shared__ __align__(16) bf16 Hs[128 * 32];
    __shared__ __align__(16) bf16 Ws[6 * 32 * 32];

    const int tid  = threadIdx.x;
    const int m0   = strip * 128;
    const int j0   = jblk * 32;            // gate-col base (0..224)
    const int wave = tid >> 6;
    const int lane = tid & 63;
    const int wm   = (wave >> 1) << 6;     // 0 / 64
    const int wn   = (wave & 1) << 4;      // 0 / 16
    const int lr   = lane & 15;
    const int kg   = lane >> 4;

    f32x4 acc[6][4] = {};                  // [gate][i] : 96 VGPRs

    const int r0 = tid >> 2;
    const int k0 = (tid & 3) << 3;

    // W staging: chunk c covers flat elements [c*2048, c*2048+2048)
    int wgate[3], wrow[3], wk[3];
#pragma unroll
    for (int c = 0; c < 3; ++c) {
        int f = c * 2048 + tid * 8;
        wgate[c] = f >> 10;                // 0..5
        wrow[c]  = (f >> 5) & 31;          // 0..31
        wk[c]    = f & 31;                 // 0,8,16,24
    }

    for (int kk = 0; kk < 256; kk += 32) {
        gl2lds16(X  + (size_t)(m0 + r0) * 256 + kk + k0,      Xs + tid * 8);
        gl2lds16(X  + (size_t)(m0 + r0 + 64) * 256 + kk + k0, Xs + 2048 + tid * 8);
        gl2lds16(Hc + (size_t)(m0 + r0) * 256 + kk + k0,      Hs + tid * 8);
        gl2lds16(Hc + (size_t)(m0 + r0 + 64) * 256 + kk + k0, Hs + 2048 + tid * 8);
#pragma unroll
        for (int c = 0; c < 3; ++c) {
            int g = wgate[c];
            const bf16* src = (g < 3)
                ? Wih + (size_t)(g * 256 + j0 + wrow[c]) * 256 + kk + wk[c]
                : Whh + (size_t)((g - 3) * 256 + j0 + wrow[c]) * 256 + kk + wk[c];
            gl2lds16(src, Ws + c * 2048 + tid * 8);
        }
        __syncthreads();

        bf16x8 af[4], ah[4], bw[6];
#pragma unroll
        for (int i = 0; i < 4; ++i) {
            af[i] = *reinterpret_cast<const bf16x8*>(&Xs[(wm + i * 16 + lr) * 32 + kg * 8]);
            ah[i] = *reinterpret_cast<const bf16x8*>(&Hs[(wm + i * 16 + lr) * 32 + kg * 8]);
        }
#pragma unroll
        for (int g = 0; g < 6; ++g)
            bw[g] = *reinterpret_cast<const bf16x8*>(&Ws[g * 1024 + (wn + lr) * 32 + kg * 8]);
#pragma unroll
        for (int g = 0; g < 3; ++g)
#pragma unroll
            for (int i = 0; i < 4; ++i)
                acc[g][i] = __builtin_amdgcn_mfma_f32_16x16x32_bf16(af[i], bw[g], acc[g][i], 0, 0, 0);
#pragma unroll
        for (int g = 3; g < 6; ++g)
#pragma unroll
            for (int i = 0; i < 4; ++i)
                acc[g][i] = __builtin_amdgcn_mfma_f32_16x16x32_bf16(ah[i], bw[g], acc[g][i], 0, 0, 0);
        __syncthreads();
    }

    const int col = j0 + wn + lr;
    const float bi_r = bih[col], bi_z = bih[256 + col], bi_n = bih[512 + col];
    const float bh_r = bhh[col], bh_z = bhh[256 + col], bh_n = bhh[512 + col];
#pragma unroll
    for (int i = 0; i < 4; ++i) {
#pragma unroll
        for (int v = 0; v < 4; ++v) {
            int row = m0 + wm + i * 16 + kg * 4 + v;
            float ir  = acc[0][i][v] + bi_r;
            float iz  = acc[1][i][v] + bi_z;
            float in_ = acc[2][i][v] + bi_n;
            float hr  = acc[3][i][v] + bh_r;
            float hz  = acc[4][i][v] + bh_z;
            float hn  = acc[5][i][v] + bh_n;
            float r = __fdividef(1.f, 1.f + __expf(-(ir + hr)));
            float z = __fdividef(1.f, 1.f + __expf(-(iz + hz)));
            float a = in_ + r * hn;
            a = fminf(fmaxf(a, -15.f), 15.f);
            float t2 = __expf(2.f * a);
            float nn = __fdividef(t2 - 1.f, t2 + 1.f);
            float hold = (float)Hc[(size_t)row * 256 + col];
            Hn[(size_t)row * 256 + col] = (bf16)((1.f - z) * nn + z * hold);
        }
    }
}

// ------------------------------------------------- conv A-matrix build ----
struct __attribute__((aligned(8))) bf4 { bf16 b[4]; };

__global__ __launch_bounds__(256) void gather_conv_k(
    const float* __restrict__ xbase, long long sB, long long sN,
    const int* __restrict__ rp0, const int* __restrict__ col0,
    const int* __restrict__ rp1, const int* __restrict__ col1,
    bf16* __restrict__ Aconv)
{
    int wid  = (blockIdx.x * 256 + threadIdx.x) >> 6;
    int lane = threadIdx.x & 63;
    if (wid >= BN_) return;
    int b = wid / N_;
    int n = wid - b * N_;
    int eg = lane >> 4;
    int cl = lane & 15;
    const float* xb = xbase + (size_t)b * sB;

    float4 xv = *reinterpret_cast<const float4*>(&xb[(size_t)n * sN + cl * 4]);

    float4 s0 = {0.f, 0.f, 0.f, 0.f};
    int st = rp0[n], en = rp0[n + 1];
    float d0 = fmaxf((float)(en - st), 1.f);
    for (int e = st + eg; e < en; e += 4) {
        const float4 v = *reinterpret_cast<const float4*>(&xb[(size_t)col0[e] * sN + cl * 4]);
        s0.x += v.x; s0.y += v.y; s0.z += v.z; s0.w += v.w;
    }

    float4 s1 = {0.f, 0.f, 0.f, 0.f};
    st = rp1[n]; en = rp1[n + 1];
    float d1 = fmaxf((float)(en - st), 1.f);
    for (int e = st + eg; e < en; e += 4) {
        const float4 v = *reinterpret_cast<const float4*>(&xb[(size_t)col1[e] * sN + cl * 4]);
        s1.x += v.x; s1.y += v.y; s1.z += v.z; s1.w += v.w;
    }

#pragma unroll
    for (int m = 16; m <= 32; m <<= 1) {
        s0.x += __shfl_xor(s0.x, m, 64); s0.y += __shfl_xor(s0.y, m, 64);
        s0.z += __shfl_xor(s0.z, m, 64); s0.w += __shfl_xor(s0.w, m, 64);
        s1.x += __shfl_xor(s1.x, m, 64); s1.y += __shfl_xor(s1.y, m, 64);
        s1.z += __shfl_xor(s1.z, m, 64); s1.w += __shfl_xor(s1.w, m, 64);
    }

    if (eg == 0) {
        float r0 = 1.f / d0, r1 = 1.f / d1;
        bf16* row = Aconv + (size_t)wid * 192;
        bf4 o;
        o.b[0] = (bf16)(s0.x * r0); o.b[1] = (bf16)(s0.y * r0);
        o.b[2] = (bf16)(s0.z * r0); o.b[3] = (bf16)(s0.w * r0);
        *reinterpret_cast<bf4*>(&row[cl * 4]) = o;
        o.b[0] = (bf16)xv.x; o.b[1] = (bf16)xv.y; o.b[2] = (bf16)xv.z; o.b[3] = (bf16)xv.w;
        *reinterpret_cast<bf4*>(&row[64 + cl * 4]) = o;
        o.b[0] = (bf16)(s1.x * r1); o.b[1] = (bf16)(s1.y * r1);
        o.b[2] = (bf16)(s1.z * r1); o.b[3] = (bf16)(s1.w * r1);
        *reinterpret_cast<bf4*>(&row[128 + cl * 4]) = o;
    }
}

// ------------------------------------------------------------ CSR build ----
__global__ void count_k(const int* __restrict__ ei, int* __restrict__ cnt) {
    int e = blockIdx.x * 256 + threadIdx.x;
    if (e < E_) atomicAdd(&cnt[ei[E_ + e]], 1);
}

__global__ __launch_bounds__(1024) void scan_k(
    const int* __restrict__ cnt, int* __restrict__ rp, int* __restrict__ fill)
{
    __shared__ int sums[1024];
    int t = threadIdx.x;
    const int chunk = 10;
    int lo = t * chunk;
    int hi = lo + chunk; if (hi > N_) hi = N_;
    int s = 0;
    for (int i = lo; i < hi; ++i) s += cnt[i];
    sums[t] = s;
    __syncthreads();
    for (int off = 1; off < 1024; off <<= 1) {
        int u = (t >= off) ? sums[t - off] : 0;
        __syncthreads();
        sums[t] += u;
        __syncthreads();
    }
    int base = (t == 0) ? 0 : sums[t - 1];
    for (int i = lo; i < hi; ++i) { rp[i] = base; fill[i] = base; base += cnt[i]; }
    if (t == 1023) rp[N_] = sums[1023];
}

__global__ void fill_k(const int* __restrict__ ei, int* __restrict__ fill,
                       int* __restrict__ colarr) {
    int e = blockIdx.x * 256 + threadIdx.x;
    if (e < E_) {
        int p = atomicAdd(&fill[ei[E_ + e]], 1);
        colarr[p] = ei[e];
    }
}

// --------------------------------------------------------- weight prep ----
__global__ void cvt_bf16_k(const float* __restrict__ s, bf16* __restrict__ d, int n) {
    int i = blockIdx.x * 256 + threadIdx.x;
    if (i < n) d[i] = (bf16)s[i];
}

__global__ void build_conv_bt_k(const float* __restrict__ Wl0, const float* __restrict__ Wr0,
                                const float* __restrict__ Wl1, const float* __restrict__ Wr1,
                                bf16* __restrict__ Bt) {
    int idx = blockIdx.x * 256 + threadIdx.x;
    if (idx >= 256 * 192) return;
    int n = idx / 192, k = idx - n * 192;
    float v;
    if (k < 64)       v = Wl0[k * 256 + n];
    else if (k < 128) v = Wr0[(k - 64) * 256 + n] + Wr1[(k - 64) * 256 + n];
    else              v = Wl1[(k - 128) * 256 + n];
    Bt[idx] = (bf16)v;
}

__global__ void build_conv_bias_k(const float* __restrict__ bl0, const float* __restrict__ bl1,
                                  float* __restrict__ bias) {
    int i = threadIdx.x;
    if (i < 256) bias[i] = bl0[i] + bl1[i];
}

__global__ void build_proj_k(const float* __restrict__ Wp, const float* __restrict__ bp,
                             bf16* __restrict__ Bt, float* __restrict__ bias) {
    int idx = blockIdx.x * 256 + threadIdx.x;
    if (idx < 128 * 256) {
        int n = idx >> 8, k = idx & 255;
        Bt[idx] = (bf16)(n < 64 ? Wp[n * 256 + k] : 0.f);
    }
    if (idx < 128) bias[idx] = (idx < 64) ? bp[idx] : 0.f;
}

// ---------------------------------------------------------------- host ----
extern "C" void kernel_launch(void* const* d_in, const int* in_sizes, int n_in,
                              void* d_out, int out_size, void* d_ws, size_t ws_size,
                              hipStream_t stream)
{
    const float* x_seq = (const float*)d_in[0];
    const int*   ei0   = (const int*)d_in[1];
    const int*   ei1   = (const int*)d_in[2];
    const float* Wl0   = (const float*)d_in[3];
    const float* bl0   = (const float*)d_in[4];
    const float* Wr0   = (const float*)d_in[5];
    const float* Wl1   = (const float*)d_in[6];
    const float* bl1   = (const float*)d_in[7];
    const float* Wr1   = (const float*)d_in[8];
    const float* Wp    = (const float*)d_in[9];
    const float* bp    = (const float*)d_in[10];
    const float* gWih[3], *gWhh[3], *gbih[3], *gbhh[3];
    for (int g = 0; g < 3; ++g) {
        gWih[g] = (const float*)d_in[11 + 4 * g];
        gWhh[g] = (const float*)d_in[12 + 4 * g];
        gbih[g] = (const float*)d_in[13 + 4 * g];
        gbhh[g] = (const float*)d_in[14 + 4 * g];
    }

    char* p = (char*)d_ws;
    auto alloc = [&](size_t bytes) -> char* {
        char* r = p; p += (bytes + 255) & ~(size_t)255; return r;
    };
    bf16*  Aconv  = (bf16*)alloc((size_t)MPAD * 192 * 2);
    bf16*  cbuf   = (bf16*)alloc((size_t)MPAD * 256 * 2);
    bf16*  hbuf[6];
    for (int g = 0; g < 6; ++g) hbuf[g] = (bf16*)alloc((size_t)MPAD * 256 * 2);
    bf16*  wih[3], *whh[3];
    for (int g = 0; g < 3; ++g) {
        wih[g] = (bf16*)alloc((size_t)768 * 256 * 2);
        whh[g] = (bf16*)alloc((size_t)768 * 256 * 2);
    }
    bf16*  btconv = (bf16*)alloc((size_t)256 * 192 * 2);
    float* bconv  = (float*)alloc(256 * 4);
    bf16*  btproj = (bf16*)alloc((size_t)128 * 256 * 2);
    float* bproj  = (float*)alloc(128 * 4);
    int* cnt0  = (int*)alloc(N_ * 4);
    int* cnt1  = (int*)alloc(N_ * 4);
    int* rp0   = (int*)alloc((N_ + 1) * 4);
    int* rp1   = (int*)alloc((N_ + 1) * 4);
    int* fill0 = (int*)alloc((N_ + 1) * 4);
    int* fill1 = (int*)alloc((N_ + 1) * 4);
    int* col0  = (int*)alloc(E_ * 4);
    int* col1  = (int*)alloc(E_ * 4);

    // h cur buffers (0,1,2) must start at zero; nxt (3,4,5) fully written.
    hipMemsetAsync(Aconv, 0, (size_t)MPAD * 192 * 2, stream);
    for (int g = 0; g < 3; ++g)
        hipMemsetAsync(hbuf[g], 0, (size_t)MPAD * 256 * 2, stream);
    hipMemsetAsync(cnt0, 0, N_ * 4, stream);
    hipMemsetAsync(cnt1, 0, N_ * 4, stream);

    for (int g = 0; g < 3; ++g) {
        cvt_bf16_k<<<768, 256, 0, stream>>>(gWih[g], wih[g], 768 * 256);
        cvt_bf16_k<<<768, 256, 0, stream>>>(gWhh[g], whh[g], 768 * 256);
    }
    build_conv_bt_k<<<192, 256, 0, stream>>>(Wl0, Wr0, Wl1, Wr1, btconv);
    build_conv_bias_k<<<1, 256, 0, stream>>>(bl0, bl1, bconv);
    build_proj_k<<<128, 256, 0, stream>>>(Wp, bp, btproj, bproj);

    count_k<<<(E_ + 255) / 256, 256, 0, stream>>>(ei0, cnt0);
    count_k<<<(E_ + 255) / 256, 256, 0, stream>>>(ei1, cnt1);
    scan_k<<<1, 1024, 0, stream>>>(cnt0, rp0, fill0);
    scan_k<<<1, 1024, 0, stream>>>(cnt1, rp1, fill1);
    fill_k<<<(E_ + 255) / 256, 256, 0, stream>>>(ei0, fill0, col0);
    fill_k<<<(E_ + 255) / 256, 256, 0, stream>>>(ei1, fill1, col1);

    bf16 *hc[3] = { hbuf[0], hbuf[1], hbuf[2] };
    bf16 *hn[3] = { hbuf[3], hbuf[4], hbuf[5] };

    auto do_conv = [&](const float* xb, long long sB, long long sN) {
        gather_conv_k<<<10000, 256, 0, stream>>>(xb, sB, sN, rp0, col0, rp1, col1, Aconv);
        gemm_k<1, 1, 1, 0><<<dim3(2, 313, 1), 256, 0, stream>>>(
            Aconv, btconv, cbuf, bconv, 192, 256, 0);
    };
    // 40 sblk groups x 8 jblk x 8 strip-low = 2560 blocks (56 early-exit)
    auto do_grus = [&]() {
        gru_fused_k<<<2560, 256, 0, stream>>>(
            cbuf, hc[0], hn[0], wih[0], whh[0], gbih[0], gbhh[0]);
        gru_fused_k<<<2560, 256, 0, stream>>>(
            hn[0], hc[1], hn[1], wih[1], whh[1], gbih[1], gbhh[1]);
        gru_fused_k<<<2560, 256, 0, stream>>>(
            hn[1], hc[2], hn[2], wih[2], whh[2], gbih[2], gbhh[2]);
        for (int g = 0; g < 3; ++g) { bf16* t = hc[g]; hc[g] = hn[g]; hn[g] = t; }
    };

    // encoder
    for (int ps = 0; ps < P_; ++ps) {
        do_conv(x_seq + (size_t)ps * N_ * C_, (long long)P_ * N_ * C_, C_);
        do_grus();
    }

    // decoder: t=0 reuses encoder step-7 conv output (same x input)
    float* out = (float*)d_out;
    for (int t = 0; t < HOR_; ++t) {
        if (t > 0)
            do_conv(out + (size_t)(t - 1) * N_ * C_, (long long)HOR_ * N_ * C_, C_);
        do_grus();
        gemm_k<1, 0, 0, 1><<<dim3(1, 313, 1), 256, 0, stream>>>(
            hc[2], btproj, out, bproj, 256, 128, t);
    }
}